// Round 1
// baseline (354.578 us; speedup 1.0000x reference)
//
#include <hip/hip_runtime.h>
#include <stdint.h>

// Problem constants (fixed by reference)
#define B_ROWS 8192
#define DH     1024      // D == H == 1024
#define KTOT   2048      // D + H (concatenated K)
#define NTOT   4096      // 4*H gate-interleaved columns

typedef __attribute__((ext_vector_type(8))) __bf16 bf16x8;
typedef __attribute__((ext_vector_type(4))) float  f32x4;

// ---------- helpers ----------
__device__ __forceinline__ unsigned short f2bf(float f) {
    unsigned int u = __float_as_uint(f);
    u += 0x7FFFu + ((u >> 16) & 1u);   // round-to-nearest-even
    return (unsigned short)(u >> 16);
}

__device__ __forceinline__ float fast_sigmoid(float x) {
    return 1.0f / (1.0f + __expf(-x));
}
__device__ __forceinline__ float fast_tanh(float x) {
    float e = __expf(fminf(-2.0f * x, 80.0f));   // clamp avoids inf/inf
    return (1.0f - e) / (1.0f + e);
}
__device__ __forceinline__ float sel4(float g0, float g1, float g2, float g3, int u) {
    float r = g0;
    r = (u == 1) ? g1 : r;
    r = (u == 2) ? g2 : r;
    r = (u == 3) ? g3 : r;
    return r;
}

// ---------- pack kernels (fp32 -> bf16, fused K-concat) ----------
// A_cat[b][k] : k<1024 -> e_t[b][k], else h_prev[b][k-1024]
__global__ __launch_bounds__(256) void pack_act(const float* __restrict__ e_t,
                                                const float* __restrict__ h_prev,
                                                unsigned short* __restrict__ A_cat) {
    int idx8 = blockIdx.x * 256 + threadIdx.x;        // one thread = 8 elements
    int row  = idx8 >> 8;                             // KTOT/8 = 256 chunks/row
    int c8   = (idx8 & 255) << 3;
    const float* src = (c8 < DH) ? (e_t + (size_t)row * DH + c8)
                                 : (h_prev + (size_t)row * DH + (c8 - DH));
    float4 f0 = ((const float4*)src)[0];
    float4 f1 = ((const float4*)src)[1];
    uint4 o;
    o.x = (unsigned)f2bf(f0.x) | ((unsigned)f2bf(f0.y) << 16);
    o.y = (unsigned)f2bf(f0.z) | ((unsigned)f2bf(f0.w) << 16);
    o.z = (unsigned)f2bf(f1.x) | ((unsigned)f2bf(f1.y) << 16);
    o.w = (unsigned)f2bf(f1.z) | ((unsigned)f2bf(f1.w) << 16);
    *(uint4*)(A_cat + (size_t)idx8 * 8) = o;
}

// W_cat row g' = h*4 + gate  <-  concat(W_x[gate*H + h][:], W_h[gate*H + h][:])
__global__ __launch_bounds__(256) void pack_wts(const float* __restrict__ W_x,
                                                const float* __restrict__ W_h,
                                                unsigned short* __restrict__ W_cat) {
    int idx8 = blockIdx.x * 256 + threadIdx.x;
    int row  = idx8 >> 8;                // g' in [0,4096)
    int c8   = (idx8 & 255) << 3;
    int h    = row >> 2;
    int gate = row & 3;
    int srow = gate * DH + h;
    const float* src = (c8 < DH) ? (W_x + (size_t)srow * DH + c8)
                                 : (W_h + (size_t)srow * DH + (c8 - DH));
    float4 f0 = ((const float4*)src)[0];
    float4 f1 = ((const float4*)src)[1];
    uint4 o;
    o.x = (unsigned)f2bf(f0.x) | ((unsigned)f2bf(f0.y) << 16);
    o.y = (unsigned)f2bf(f0.z) | ((unsigned)f2bf(f0.w) << 16);
    o.z = (unsigned)f2bf(f1.x) | ((unsigned)f2bf(f1.y) << 16);
    o.w = (unsigned)f2bf(f1.z) | ((unsigned)f2bf(f1.w) << 16);
    *(uint4*)(W_cat + (size_t)idx8 * 8) = o;
}

__global__ __launch_bounds__(256) void pack_bias(const float* __restrict__ b_x,
                                                 const float* __restrict__ b_h,
                                                 const float* __restrict__ b_e,
                                                 float* __restrict__ bias) {
    int gp = blockIdx.x * 256 + threadIdx.x;   // g' in [0,4096)
    int h = gp >> 2, gate = gp & 3;
    int g = gate * DH + h;
    bias[gp] = b_x[g] + b_h[g] + b_e[g];
}

// ---------- fused GEMM + LSTM epilogue ----------
// C[m, g'] = sum_k A_cat[m,k] * W_cat[g',k]  (+bias), then per-h gate math.
// 128x128 block tile, BK=64, 4 waves in 2x2, each wave 64x64 via 4x4 MFMA 16x16x32.
__global__ __launch_bounds__(256) void lstm_gemm(const unsigned short* __restrict__ A,
                                                 const unsigned short* __restrict__ Wc,
                                                 const float* __restrict__ bias,
                                                 const float* __restrict__ c_prev,
                                                 float* __restrict__ h_out,
                                                 float* __restrict__ c_out) {
    __shared__ __align__(16) unsigned char As[128 * 64 * 2];
    __shared__ __align__(16) unsigned char Bs[128 * 64 * 2];

    const int tid = threadIdx.x;
    const int w   = tid >> 6;          // wave 0..3
    const int l   = tid & 63;          // lane
    const int wm  = w >> 1, wn = w & 1;
    const int m0  = blockIdx.y * 128;
    const int n0  = blockIdx.x * 128;

    f32x4 acc[4][4];
#pragma unroll
    for (int i = 0; i < 4; ++i)
#pragma unroll
        for (int j = 0; j < 4; ++j) acc[i][j] = {0.f, 0.f, 0.f, 0.f};

    // staging: per wave w, issue i: LDS bytes [w*4096 + i*1024 + l*16]
    // -> element idx = w*2048 + i*512 + l*8 -> row = w*32+i*8+(l>>3), col=(l&7)*8
    const int srow = w * 32 + (l >> 3);
    const int scol = (l & 7) * 8;
    const unsigned short* gA = A  + (size_t)(m0 + srow) * KTOT + scol;
    const unsigned short* gB = Wc + (size_t)(n0 + srow) * KTOT + scol;
    unsigned char* lA = As + w * 4096;
    unsigned char* lB = Bs + w * 4096;

    const int lane15 = l & 15;
    const int quad   = l >> 4;

    for (int kt = 0; kt < KTOT / 64; ++kt) {
#pragma unroll
        for (int i = 0; i < 4; ++i) {
            __builtin_amdgcn_global_load_lds(
                (const __attribute__((address_space(1))) void*)(gA + (size_t)(i * 8) * KTOT + kt * 64),
                (__attribute__((address_space(3))) void*)(lA + i * 1024), 16, 0, 0);
            __builtin_amdgcn_global_load_lds(
                (const __attribute__((address_space(1))) void*)(gB + (size_t)(i * 8) * KTOT + kt * 64),
                (__attribute__((address_space(3))) void*)(lB + i * 1024), 16, 0, 0);
        }
        __syncthreads();   // drains vmcnt before barrier (compiler-enforced)

#pragma unroll
        for (int ks = 0; ks < 2; ++ks) {
            bf16x8 af[4], bfr[4];
#pragma unroll
            for (int mi = 0; mi < 4; ++mi)
                af[mi] = *(const bf16x8*)(As + (wm * 64 + mi * 16 + lane15) * 128 + ks * 64 + quad * 16);
#pragma unroll
            for (int ni = 0; ni < 4; ++ni)
                bfr[ni] = *(const bf16x8*)(Bs + (wn * 64 + ni * 16 + lane15) * 128 + ks * 64 + quad * 16);
#pragma unroll
            for (int mi = 0; mi < 4; ++mi)
#pragma unroll
                for (int ni = 0; ni < 4; ++ni)
                    acc[mi][ni] = __builtin_amdgcn_mfma_f32_16x16x32_bf16(af[mi], bfr[ni], acc[mi][ni], 0, 0, 0);
        }
        __syncthreads();
    }

    // ---------- fused LSTM epilogue ----------
    // C/D layout (verified m89/m91): col = lane&15 (n), row = quad*4 + reg (m).
    // Gate interleave: n = h*4 + gate -> gates of one h live in lane quads.
    float biasv[4];
#pragma unroll
    for (int nj = 0; nj < 4; ++nj)
        biasv[nj] = bias[n0 + wn * 64 + nj * 16 + lane15];

    const int u = (l >> 2) & 3;                 // reg (row-sub) this lane outputs
    const int v = l & 3;                        // h-sub this lane outputs
    const int src_base = (l & 0x30) | (v << 2); // quad-preserving gather base
    const int hbase = (n0 + wn * 64) >> 2;

#pragma unroll
    for (int mi = 0; mi < 4; ++mi) {
        const int m = m0 + wm * 64 + mi * 16 + quad * 4 + u;
#pragma unroll
        for (int nj = 0; nj < 4; ++nj) {
            f32x4 a = acc[mi][nj];
            float bb = biasv[nj];
            float a0 = a[0] + bb, a1 = a[1] + bb, a2 = a[2] + bb, a3 = a[3] + bb;

            float s0, s1, s2, s3;
            s0 = __shfl(a0, src_base | 0, 64); s1 = __shfl(a1, src_base | 0, 64);
            s2 = __shfl(a2, src_base | 0, 64); s3 = __shfl(a3, src_base | 0, 64);
            float zf = sel4(s0, s1, s2, s3, u);
            s0 = __shfl(a0, src_base | 1, 64); s1 = __shfl(a1, src_base | 1, 64);
            s2 = __shfl(a2, src_base | 1, 64); s3 = __shfl(a3, src_base | 1, 64);
            float zi = sel4(s0, s1, s2, s3, u);
            s0 = __shfl(a0, src_base | 2, 64); s1 = __shfl(a1, src_base | 2, 64);
            s2 = __shfl(a2, src_base | 2, 64); s3 = __shfl(a3, src_base | 2, 64);
            float zo = sel4(s0, s1, s2, s3, u);
            s0 = __shfl(a0, src_base | 3, 64); s1 = __shfl(a1, src_base | 3, 64);
            s2 = __shfl(a2, src_base | 3, 64); s3 = __shfl(a3, src_base | 3, 64);
            float zc = sel4(s0, s1, s2, s3, u);

            float gf = fast_sigmoid(zf);
            float gi = fast_sigmoid(zi);
            float go = fast_sigmoid(zo);
            float mh = fast_tanh(zc);

            const int h = hbase + nj * 4 + v;
            const size_t off = (size_t)m * DH + h;
            float cp = c_prev[off];
            float ct = gf * cp + gi * mh;
            float ht = go * fast_tanh(ct);
            h_out[off] = ht;
            c_out[off] = ct;
        }
    }
}

// ---------- launch ----------
extern "C" void kernel_launch(void* const* d_in, const int* in_sizes, int n_in,
                              void* d_out, int out_size, void* d_ws, size_t ws_size,
                              hipStream_t stream) {
    const float* e_t     = (const float*)d_in[0];
    const float* h_prev  = (const float*)d_in[1];
    const float* c_prev  = (const float*)d_in[2];
    const float* W_x     = (const float*)d_in[3];
    const float* b_x     = (const float*)d_in[4];
    const float* W_h     = (const float*)d_in[5];
    const float* b_h     = (const float*)d_in[6];
    const float* b_extra = (const float*)d_in[7];

    float* h_out = (float*)d_out;
    float* c_out = h_out + (size_t)B_ROWS * DH;

    // workspace layout: A_cat (32MB) | W_cat (16MB) | bias (16KB)
    unsigned short* A_cat = (unsigned short*)d_ws;
    unsigned short* W_cat = (unsigned short*)((char*)d_ws + (size_t)B_ROWS * KTOT * 2);
    float*          bias  = (float*)((char*)d_ws + (size_t)B_ROWS * KTOT * 2 + (size_t)NTOT * KTOT * 2);

    pack_act <<<B_ROWS * KTOT / 8 / 256, 256, 0, stream>>>(e_t, h_prev, A_cat);
    pack_wts <<<NTOT   * KTOT / 8 / 256, 256, 0, stream>>>(W_x, W_h, W_cat);
    pack_bias<<<NTOT / 256,              256, 0, stream>>>(b_x, b_h, b_extra, bias);
    lstm_gemm<<<dim3(NTOT / 128, B_ROWS / 128), 256, 0, stream>>>(A_cat, W_cat, bias, c_prev, h_out, c_out);
}

// Round 2
// 350.658 us; speedup vs baseline: 1.0112x; 1.0112x over previous
//
#include <hip/hip_runtime.h>
#include <stdint.h>

// Problem constants (fixed by reference)
#define B_ROWS 8192
#define DH     1024      // D == H == 1024
#define KTOT   2048      // D + H (concatenated K)
#define NTOT   4096      // 4*H gate-interleaved columns

typedef __attribute__((ext_vector_type(8))) __bf16 bf16x8;
typedef __attribute__((ext_vector_type(4))) float  f32x4;

// ---------- helpers ----------
__device__ __forceinline__ unsigned short f2bf(float f) {
    unsigned int u = __float_as_uint(f);
    u += 0x7FFFu + ((u >> 16) & 1u);   // round-to-nearest-even
    return (unsigned short)(u >> 16);
}

__device__ __forceinline__ float fast_sigmoid(float x) {
    return 1.0f / (1.0f + __expf(-x));
}
__device__ __forceinline__ float fast_tanh(float x) {
    float e = __expf(fminf(-2.0f * x, 80.0f));   // clamp avoids inf/inf
    return (1.0f - e) / (1.0f + e);
}
__device__ __forceinline__ float sel4(float g0, float g1, float g2, float g3, int u) {
    float r = g0;
    r = (u == 1) ? g1 : r;
    r = (u == 2) ? g2 : r;
    r = (u == 3) ? g3 : r;
    return r;
}

// ---------- single fused pack kernel ----------
// blocks [0, 8192)                : A_cat rows   (e_t | h_prev -> bf16)
// blocks [8192, 8192+4096)        : W_cat rows   (gate-interleaved W_x|W_h -> bf16)
// blocks [8192+4096, +16)         : bias  (b_x + b_h + b_extra, gate-interleaved)
#define NBLK_A (B_ROWS)            // one block packs one 2048-elem row
#define NBLK_W (NTOT)
#define NBLK_BIAS (NTOT / 256)

__global__ __launch_bounds__(256) void pack_all(const float* __restrict__ e_t,
                                                const float* __restrict__ h_prev,
                                                const float* __restrict__ W_x,
                                                const float* __restrict__ W_h,
                                                const float* __restrict__ b_x,
                                                const float* __restrict__ b_h,
                                                const float* __restrict__ b_e,
                                                unsigned short* __restrict__ A_cat,
                                                unsigned short* __restrict__ W_cat,
                                                float* __restrict__ bias) {
    const int blk = blockIdx.x;
    const int t   = threadIdx.x;
    if (blk < NBLK_A + NBLK_W) {
        // pack one row of A_cat or W_cat: 2048 elements = 256 threads x 8
        const float* src0;
        unsigned short* dst;
        int row;
        if (blk < NBLK_A) {
            row = blk;
            src0 = nullptr;  // chosen below
            dst = A_cat + (size_t)row * KTOT;
            int c8 = t << 3;
            src0 = (c8 < DH) ? (e_t + (size_t)row * DH + c8)
                             : (h_prev + (size_t)row * DH + (c8 - DH));
        } else {
            row = blk - NBLK_A;                 // g' = h*4 + gate
            int h = row >> 2, gate = row & 3;
            int srow = gate * DH + h;
            dst = W_cat + (size_t)row * KTOT;
            int c8 = t << 3;
            src0 = (c8 < DH) ? (W_x + (size_t)srow * DH + c8)
                             : (W_h + (size_t)srow * DH + (c8 - DH));
        }
        float4 f0 = ((const float4*)src0)[0];
        float4 f1 = ((const float4*)src0)[1];
        uint4 o;
        o.x = (unsigned)f2bf(f0.x) | ((unsigned)f2bf(f0.y) << 16);
        o.y = (unsigned)f2bf(f0.z) | ((unsigned)f2bf(f0.w) << 16);
        o.z = (unsigned)f2bf(f1.x) | ((unsigned)f2bf(f1.y) << 16);
        o.w = (unsigned)f2bf(f1.z) | ((unsigned)f2bf(f1.w) << 16);
        *(uint4*)(dst + t * 8) = o;
    } else {
        int gp = (blk - NBLK_A - NBLK_W) * 256 + t;   // g' in [0,4096)
        int h = gp >> 2, gate = gp & 3;
        int g = gate * DH + h;
        bias[gp] = b_x[g] + b_h[g] + b_e[g];
    }
}

// ---------- fused GEMM + LSTM epilogue ----------
// C[m, g'] = sum_k A_cat[m,k] * W_cat[g',k]  (+bias), then per-h gate math.
// 128x128 block tile, BK=64, 4 waves in 2x2, each wave 64x64 via 4x4 MFMA 16x16x32.
//
// LDS XOR-swizzle (bank-conflict fix): logical granule g (16B) of row r is
// stored at physical granule p = g ^ (r & 7).  global_load_lds's lane->LDS
// mapping is fixed, so the swizzle is applied on the *source* address:
// lane l sources col-granule (l&7) ^ ((l>>3)&7)  (wave/issue offsets are 0 mod 8).
// Fragment reads hit p = (ks*4+quad) ^ (lane15&7) -> 8 distinct bank-quads,
// 2-way aliasing = free (m136), vs 16-way before.
__global__ __launch_bounds__(256) void lstm_gemm(const unsigned short* __restrict__ A,
                                                 const unsigned short* __restrict__ Wc,
                                                 const float* __restrict__ bias,
                                                 const float* __restrict__ c_prev,
                                                 float* __restrict__ h_out,
                                                 float* __restrict__ c_out) {
    __shared__ __align__(16) unsigned char As[128 * 64 * 2];
    __shared__ __align__(16) unsigned char Bs[128 * 64 * 2];

    const int tid = threadIdx.x;
    const int w   = tid >> 6;          // wave 0..3
    const int l   = tid & 63;          // lane
    const int wm  = w >> 1, wn = w & 1;
    const int m0  = blockIdx.y * 128;
    const int n0  = blockIdx.x * 128;

    f32x4 acc[4][4];
#pragma unroll
    for (int i = 0; i < 4; ++i)
#pragma unroll
        for (int j = 0; j < 4; ++j) acc[i][j] = {0.f, 0.f, 0.f, 0.f};

    // staging: wave w, issue i, lane l -> LDS byte w*4096 + i*1024 + l*16
    //   -> tile row = w*32 + i*8 + (l>>3), physical granule p = l&7
    //   -> source logical granule g = p ^ (row&7) = (l&7) ^ ((l>>3)&7)
    const int srow = w * 32 + (l >> 3);
    const int scol = (((l & 7) ^ ((l >> 3) & 7))) * 8;   // element offset in 64-wide K-tile
    const unsigned short* gA = A  + (size_t)(m0 + srow) * KTOT + scol;
    const unsigned short* gB = Wc + (size_t)(n0 + srow) * KTOT + scol;
    unsigned char* lA = As + w * 4096;
    unsigned char* lB = Bs + w * 4096;

    const int lane15 = l & 15;
    const int quad   = l >> 4;
    // physical granule offsets for the two ks halves (swizzled)
    const int xg0 = ((0 * 4 + quad) ^ (lane15 & 7)) * 16;
    const int xg1 = ((1 * 4 + quad) ^ (lane15 & 7)) * 16;

    for (int kt = 0; kt < KTOT / 64; ++kt) {
#pragma unroll
        for (int i = 0; i < 4; ++i) {
            __builtin_amdgcn_global_load_lds(
                (const __attribute__((address_space(1))) void*)(gA + (size_t)(i * 8) * KTOT + kt * 64),
                (__attribute__((address_space(3))) void*)(lA + i * 1024), 16, 0, 0);
            __builtin_amdgcn_global_load_lds(
                (const __attribute__((address_space(1))) void*)(gB + (size_t)(i * 8) * KTOT + kt * 64),
                (__attribute__((address_space(3))) void*)(lB + i * 1024), 16, 0, 0);
        }
        __syncthreads();

#pragma unroll
        for (int ks = 0; ks < 2; ++ks) {
            const int xg = ks ? xg1 : xg0;
            bf16x8 af[4], bfr[4];
#pragma unroll
            for (int mi = 0; mi < 4; ++mi)
                af[mi] = *(const bf16x8*)(As + (wm * 64 + mi * 16 + lane15) * 128 + xg);
#pragma unroll
            for (int ni = 0; ni < 4; ++ni)
                bfr[ni] = *(const bf16x8*)(Bs + (wn * 64 + ni * 16 + lane15) * 128 + xg);
#pragma unroll
            for (int mi = 0; mi < 4; ++mi)
#pragma unroll
                for (int ni = 0; ni < 4; ++ni)
                    acc[mi][ni] = __builtin_amdgcn_mfma_f32_16x16x32_bf16(af[mi], bfr[ni], acc[mi][ni], 0, 0, 0);
        }
        __syncthreads();
    }

    // ---------- fused LSTM epilogue ----------
    // C/D layout (verified m89/m91): col = lane&15 (n), row = quad*4 + reg (m).
    // Gate interleave: n = h*4 + gate -> gates of one h live in lane quads.
    float biasv[4];
#pragma unroll
    for (int nj = 0; nj < 4; ++nj)
        biasv[nj] = bias[n0 + wn * 64 + nj * 16 + lane15];

    const int u = (l >> 2) & 3;                 // reg (row-sub) this lane outputs
    const int v = l & 3;                        // h-sub this lane outputs
    const int src_base = (l & 0x30) | (v << 2); // quad-preserving gather base
    const int hbase = (n0 + wn * 64) >> 2;

#pragma unroll
    for (int mi = 0; mi < 4; ++mi) {
        const int m = m0 + wm * 64 + mi * 16 + quad * 4 + u;
#pragma unroll
        for (int nj = 0; nj < 4; ++nj) {
            f32x4 a = acc[mi][nj];
            float bb = biasv[nj];
            float a0 = a[0] + bb, a1 = a[1] + bb, a2 = a[2] + bb, a3 = a[3] + bb;

            float s0, s1, s2, s3;
            s0 = __shfl(a0, src_base | 0, 64); s1 = __shfl(a1, src_base | 0, 64);
            s2 = __shfl(a2, src_base | 0, 64); s3 = __shfl(a3, src_base | 0, 64);
            float zf = sel4(s0, s1, s2, s3, u);
            s0 = __shfl(a0, src_base | 1, 64); s1 = __shfl(a1, src_base | 1, 64);
            s2 = __shfl(a2, src_base | 1, 64); s3 = __shfl(a3, src_base | 1, 64);
            float zi = sel4(s0, s1, s2, s3, u);
            s0 = __shfl(a0, src_base | 2, 64); s1 = __shfl(a1, src_base | 2, 64);
            s2 = __shfl(a2, src_base | 2, 64); s3 = __shfl(a3, src_base | 2, 64);
            float zo = sel4(s0, s1, s2, s3, u);
            s0 = __shfl(a0, src_base | 3, 64); s1 = __shfl(a1, src_base | 3, 64);
            s2 = __shfl(a2, src_base | 3, 64); s3 = __shfl(a3, src_base | 3, 64);
            float zc = sel4(s0, s1, s2, s3, u);

            float gf = fast_sigmoid(zf);
            float gi = fast_sigmoid(zi);
            float go = fast_sigmoid(zo);
            float mh = fast_tanh(zc);

            const int h = hbase + nj * 4 + v;
            const size_t off = (size_t)m * DH + h;
            float cp = c_prev[off];
            float ct = gf * cp + gi * mh;
            float ht = go * fast_tanh(ct);
            h_out[off] = ht;
            c_out[off] = ct;
        }
    }
}

// ---------- launch ----------
extern "C" void kernel_launch(void* const* d_in, const int* in_sizes, int n_in,
                              void* d_out, int out_size, void* d_ws, size_t ws_size,
                              hipStream_t stream) {
    const float* e_t     = (const float*)d_in[0];
    const float* h_prev  = (const float*)d_in[1];
    const float* c_prev  = (const float*)d_in[2];
    const float* W_x     = (const float*)d_in[3];
    const float* b_x     = (const float*)d_in[4];
    const float* W_h     = (const float*)d_in[5];
    const float* b_h     = (const float*)d_in[6];
    const float* b_extra = (const float*)d_in[7];

    float* h_out = (float*)d_out;
    float* c_out = h_out + (size_t)B_ROWS * DH;

    // workspace layout: A_cat (32MB) | W_cat (16MB) | bias (16KB)
    unsigned short* A_cat = (unsigned short*)d_ws;
    unsigned short* W_cat = (unsigned short*)((char*)d_ws + (size_t)B_ROWS * KTOT * 2);
    float*          bias  = (float*)((char*)d_ws + (size_t)B_ROWS * KTOT * 2 + (size_t)NTOT * KTOT * 2);

    pack_all<<<NBLK_A + NBLK_W + NBLK_BIAS, 256, 0, stream>>>(
        e_t, h_prev, W_x, W_h, b_x, b_h, b_extra, A_cat, W_cat, bias);
    lstm_gemm<<<dim3(NTOT / 128, B_ROWS / 128), 256, 0, stream>>>(
        A_cat, W_cat, bias, c_prev, h_out, c_out);
}